// Round 6
// baseline (312.217 us; speedup 1.0000x reference)
//
#include <hip/hip_runtime.h>
#include <hip/hip_bf16.h>

// Encoder_multi: zero-state single-step bidirectional 2-layer LSTM.
// h0=c0=0 => no recurrence, W_hh unused, forget gate dead.
//   gates = inp @ W_ih^T + (b_ih+b_hh); c = sig(i)*tanh(g); h = sig(o)*tanh(c)
// Two GEMMs: (8192 x 3072 x 512) and (8192 x 3072 x 1024).
//
// Round-8: RESUBMISSION of round-7 (container infra failure, no kernel verdict).
// Audited for hang paths: barriers uniform across all 8 waves / all iterations;
// vmcnt(6) count uniform (6 loads/thread/stage); no WAR race on LDS dbuf;
// 88KB static LDS < 160KB gfx950 limit (128KB precedent in 8-phase template).
//
// Round-7 changes vs round-6 (287.6 us; gemm1 64.5, MfmaUtil 35.5%):
//  * BK 32 -> 64: 192 MFMA (932 cy) per barrier-pair instead of 96 (466 cy).
//    The measured ~850 cy/step of barrier/lockstep overhead is fixed-cost; at
//    BK=64 it amortizes over 2x the math. NT 32 -> 16.
//  * 2 buffers x (A 32KB + B 12KB) = 88KB LDS -> 1 block/CU (template regime).
//    Depth-1 prefetch now spans a ~1000-cy compute phase >= miss latency, so
//    the depth-2 triple-buffer (which bought only 2.8 us) is dropped.
//  * Uniform 6 loads/thread/stage (4 A + 2 B; waves 6-7 duplicate waves 4-5's
//    second B chunk, same src+dst, benign) -> vmcnt(6) == prev stage landed.
//
// ws layout (bytes), all 16B-aligned:
//   flag  @ 0
//   bc0   @ 1024        12,288  (3072 f32 combined bias, gate-interleaved)
//   bc1   @ 16384       12,288
//   Wp0   @ 32768       3,145,728   (k-major chunks [64][3072])
//   Wp1   @ 4194304     6,291,456   (k-major chunks [128][3072])
//   e0    @ 10485760    8,388,608   (k-major chunks [64][8192])
//   inp1  @ 18874368    16,777,216  (k-major chunks [128][8192])

using bf16x8 = __attribute__((ext_vector_type(8))) short;
using f32x4  = __attribute__((ext_vector_type(4))) float;

__device__ __forceinline__ unsigned short f2bf(float f)
{
    __hip_bfloat16 h = __float2bfloat16(f);
    return *(unsigned short*)&h;
}
__device__ __forceinline__ float sigf(float x)  { return 1.0f / (1.0f + __expf(-x)); }
__device__ __forceinline__ float tanhfast(float x)
{
    return 1.0f - 2.0f / (__expf(2.0f * x) + 1.0f);
}

__device__ __forceinline__ void gload16(const void* g, void* l)
{
    __builtin_amdgcn_global_load_lds(
        (const __attribute__((address_space(1))) unsigned int*)g,
        (__attribute__((address_space(3))) unsigned int*)l, 16, 0, 0);
}
// raw barrier, fenced so ds_reads/MFMA can't cross it at schedule time (rule #18)
#define SBAR() do { __builtin_amdgcn_sched_barrier(0); \
                    __builtin_amdgcn_s_barrier();      \
                    __builtin_amdgcn_sched_barrier(0); } while (0)

// ---- single prep dispatch: detect + transpose-gather + transpose-pack + bias ----
// blocks: [0,256) e0T (32 m x 64 k8 tiles) | [256,352) Wp0 (32 n x 64 k8)
//         [352,544) Wp1 (32 n x 64 k8, 2 k8-halves) | [544,568) bias; 544 -> flag
__global__ __launch_bounds__(256)
void prep(const int* __restrict__ x, const void* __restrict__ emb,
          const void* __restrict__ Wih0, const void* __restrict__ Wih1,
          const void* __restrict__ bih0, const void* __restrict__ bhh0,
          const void* __restrict__ bih1, const void* __restrict__ bhh1,
          uint4* __restrict__ e0, uint4* __restrict__ Wp0, uint4* __restrict__ Wp1,
          float* __restrict__ bc0, float* __restrict__ bc1, int* __restrict__ flag)
{
    __shared__ int oks[4];
    __shared__ uint4 panel[32][65];             // +1 chunk pad: 4-way on T-read
    {
        unsigned lo = ((const unsigned int*)emb)[threadIdx.x] & 0xFFFFu;
        int e = (lo >> 7) & 0xFF;
        int ok = ((e >= 96 && e < 160) || lo == 0) ? 1 : 0;
#pragma unroll
        for (int off = 32; off; off >>= 1) ok += __shfl_down(ok, off);
        if ((threadIdx.x & 63) == 0) oks[threadIdx.x >> 6] = ok;
    }
    __syncthreads();
    const bool isbf = (oks[0] + oks[1] + oks[2] + oks[3]) >= 192;
    const int bid = blockIdx.x, tid = threadIdx.x;

    if (bid < 256) {                            // ---- e0T: rows read coalesced ----
        const int mbase = bid * 32;
#pragma unroll
        for (int j = 0; j < 8; ++j) {
            int li = j * 256 + tid;
            int ml = li >> 6, k8 = li & 63;     // 64 lanes: same row, consec k8
            long srow = x[mbase + ml];
            uint4 v;
            if (isbf) {
                v = ((const uint4*)emb)[srow * 64 + k8];
            } else {
                const float4* ef = (const float4*)emb;
                float4 a = ef[srow * 128 + k8 * 2], b = ef[srow * 128 + k8 * 2 + 1];
                unsigned short h[8] = { f2bf(a.x), f2bf(a.y), f2bf(a.z), f2bf(a.w),
                                        f2bf(b.x), f2bf(b.y), f2bf(b.z), f2bf(b.w) };
                v = *(uint4*)h;
            }
            panel[ml][k8] = v;
        }
        __syncthreads();
#pragma unroll
        for (int j = 0; j < 8; ++j) {           // k-major write, 512B contiguous
            int li = j * 256 + tid;
            int k8 = li >> 5, ml = li & 31;
            e0[(long)k8 * 8192 + mbase + ml] = panel[ml][k8];
        }
    } else if (bid < 544) {                     // ---- pack WpT ----
        const bool L0 = bid < 352;
        const int t = L0 ? (bid - 256) : (bid - 352);
        const int nbase  = (L0 ? t : (t >> 1)) * 32;
        const int k8base = L0 ? 0 : (t & 1) * 64;
        const void* src = L0 ? Wih0 : Wih1;
        uint4* dst = L0 ? Wp0 : Wp1;
        const int K8s = L0 ? 64 : 128;
#pragma unroll
        for (int j = 0; j < 8; ++j) {
            int li = j * 256 + tid;
            int nl = li >> 6, k8l = li & 63;    // 64 lanes: same src row, consec k8
            int n = nbase + nl;                 // gate-interleaved row n = h*6+gi
            int h = n / 6, gi = n - h * 6;
            int dir = (gi >= 3) ? 1 : 0;
            int gate = gi - dir * 3;            // 0:i 1:g 2:o
            int sg = (gate == 0) ? 0 : (gate + 1);
            long srcrow = dir * 2048 + sg * 512 + h;
            uint4 v;
            if (isbf) {
                v = ((const uint4*)src)[srcrow * K8s + k8base + k8l];
            } else {
                const float4* sf = (const float4*)src;
                long c2 = (srcrow * K8s + k8base + k8l) * 2;
                float4 a = sf[c2], b = sf[c2 + 1];
                unsigned short h8[8] = { f2bf(a.x), f2bf(a.y), f2bf(a.z), f2bf(a.w),
                                         f2bf(b.x), f2bf(b.y), f2bf(b.z), f2bf(b.w) };
                v = *(uint4*)h8;
            }
            panel[nl][k8l] = v;
        }
        __syncthreads();
#pragma unroll
        for (int j = 0; j < 8; ++j) {
            int li = j * 256 + tid;
            int k8l = li >> 5, nl = li & 31;
            dst[(long)(k8base + k8l) * 3072 + nbase + nl] = panel[nl][k8l];
        }
    } else {                                    // ---- bias ----
        int b2 = bid - 544;
        if (b2 == 0 && tid == 0) *flag = isbf ? 1 : 0;
        const bool L0 = b2 < 12;
        int n = (L0 ? b2 : (b2 - 12)) * 256 + tid;
        int h = n / 6, gi = n - h * 6;
        int dir = (gi >= 3) ? 1 : 0;
        int gate = gi - dir * 3;
        int sg = (gate == 0) ? 0 : (gate + 1);
        int s = dir * 2048 + sg * 512 + h;
        const void* bi = L0 ? bih0 : bih1;
        const void* bh = L0 ? bhh0 : bhh1;
        float* bc = L0 ? bc0 : bc1;
        float vi, vh;
        if (isbf) {
            vi = __bfloat162float(((const __hip_bfloat16*)bi)[s]);
            vh = __bfloat162float(((const __hip_bfloat16*)bh)[s]);
        } else {
            vi = ((const float*)bi)[s];
            vh = ((const float*)bh)[s];
        }
        bc[n] = vi + vh;
    }
}

// ---- fused GEMM + activation epilogue, BK=64 double-buffer, counted vmcnt ----
// C(M x 3072) = A(M x K) * B(3072 x K)^T; A,B k-major 16B chunks:
// A chunk = k8*8192 + m, B chunk = k8*3072 + n.
// Tile 256x96x64, 512 thr = 8 waves (4 row x 2 col), wave 64x48 = 4x3x2 = 24 MFMA.
// LDS: B 2x12K @0 | A 2x32K @24576 = 88KB (1 block/CU).
// Per K-step: stage(t+1) [6 loads/thread] -> vmcnt(6) (stage t landed; t+1 in
// flight across the ~1000cy compute) -> SBAR -> 14 ds_read + 24 MFMA -> SBAR.
// d_out flat: h_last(2,32,512) @0 | c_last(2,32,512) @32768 | enc(B,T,2,H) @65536
template <int LAYER, int K>
__global__ __launch_bounds__(512)
void gemm_fused(const unsigned short* __restrict__ A,
                const unsigned short* __restrict__ Bp,
                const float* __restrict__ bc,
                unsigned short* __restrict__ inp1,
                void* __restrict__ outv,
                const int* __restrict__ flag)
{
    constexpr int NT = K / 64;
    __shared__ __align__(16) char smem[90112];

    const int tid = threadIdx.x;
    // XCD swizzle: contiguous bm-range per XCD, bn fastest.
    const int raw = blockIdx.x + (blockIdx.y << 5);     // grid 32x32
    const int xcd = raw & 7, local = raw >> 3;
    const int bm = xcd * 4 + (local >> 5);
    const int bn = local & 31;

    const uint4* a4 = (const uint4*)A;
    const uint4* b4 = (const uint4*)Bp;

    // A: LDS chunk c = k8l*256+row (k8l 0..7); thread owns c = tid + j*512, j=0..3.
    // B: LDS chunk c = k8l*96+n; thread owns btid and btid+384 (waves 6-7 mirror
    //    waves 4-5 -> uniform 2 B loads/thread).
    const int btid = (tid < 384) ? tid : (tid - 128);
    const long aOff = (long)(tid >> 8) * 8192 + bm * 256 + (tid & 255);
    const long bOff = (long)(btid / 96) * 3072 + bn * 96 + (btid % 96);

    const int wave = tid >> 6, lane = tid & 63;
    const int wr = (wave >> 1) * 64;                    // 0/64/128/192
    const int wc = (wave & 1) * 48;                     // 0/48
    const int lr = lane & 15, q = lane >> 4;

    f32x4 acc[4][3] = {};

    auto stage = [&](int s) {
        const int buf = s & 1;
        uint4* As4 = (uint4*)(smem + 24576 + buf * 32768);
        uint4* Bs4 = (uint4*)(smem + buf * 12288);
        const uint4* ap = a4 + (long)s * 65536 + aOff;  // 8 k8-slices per stage
        gload16(ap,          As4 + tid);
        gload16(ap + 16384,  As4 + tid + 512);
        gload16(ap + 32768,  As4 + tid + 1024);
        gload16(ap + 49152,  As4 + tid + 1536);
        const uint4* bp = b4 + (long)s * 24576 + bOff;
        gload16(bp,          Bs4 + btid);
        gload16(bp + 12288,  Bs4 + btid + 384);
    };

    stage(0);
#pragma unroll
    for (int t = 0; t < NT; ++t) {
        if (t + 1 < NT) {
            stage(t + 1);
            asm volatile("s_waitcnt vmcnt(6)" ::: "memory");    // stage(t) landed
        } else {
            asm volatile("s_waitcnt vmcnt(0)" ::: "memory");
        }
        SBAR();                                         // buf[t] visible to all waves

        const unsigned short* As = (const unsigned short*)(smem + 24576 + (t & 1) * 32768);
        const unsigned short* Bs = (const unsigned short*)(smem + (t & 1) * 12288);
        bf16x8 af[2][4], bfr[2][3];
#pragma unroll
        for (int s = 0; s < 2; ++s) {
#pragma unroll
            for (int i = 0; i < 4; ++i)                 // chunk = (s*4+q)*256 + row
                af[s][i] = *(const bf16x8*)&As[((s * 4 + q) * 256 + wr + i * 16 + lr) * 8];
#pragma unroll
            for (int j = 0; j < 3; ++j)                 // chunk = (s*4+q)*96 + n
                bfr[s][j] = *(const bf16x8*)&Bs[((s * 4 + q) * 96 + wc + j * 16 + lr) * 8];
        }
        __builtin_amdgcn_s_setprio(1);
#pragma unroll
        for (int s = 0; s < 2; ++s)
#pragma unroll
            for (int i = 0; i < 4; ++i)
#pragma unroll
                for (int j = 0; j < 3; ++j)
                    acc[i][j] = __builtin_amdgcn_mfma_f32_16x16x32_bf16(af[s][i], bfr[s][j], acc[i][j], 0, 0, 0);
        __builtin_amdgcn_s_setprio(0);
        SBAR();                                         // all reads of buf[t] done
    }

    // ---- fused epilogue: Cs[64][97] overlays LDS (all staging drained) ----
    float* Cs = (float*)smem;
    const bool isbf = (*flag != 0);
    auto store = [&](long i, float v) {
        if (isbf) ((__hip_bfloat16*)outv)[i] = __float2bfloat16(v);
        else      ((float*)outv)[i] = v;
    };

    const int hl = tid & 15;
    float bcv[6];
#pragma unroll
    for (int gi = 0; gi < 6; ++gi) bcv[gi] = bc[bn * 96 + hl * 6 + gi];

    for (int p = 0; p < 4; ++p) {                       // 64 rows per pass
        if ((wave >> 1) == p) {
            // D layout: col = lane&15, row = (lane>>4)*4 + reg (m89/m91-verified)
#pragma unroll
            for (int i = 0; i < 4; ++i)
#pragma unroll
                for (int j = 0; j < 3; ++j)
#pragma unroll
                    for (int r = 0; r < 4; ++r)
                        Cs[(i * 16 + q * 4 + r) * 97 + wc + j * 16 + lr] = acc[i][j][r];
        }
        __syncthreads();
#pragma unroll
        for (int t2 = 0; t2 < 2; ++t2) {
            int ml = (tid >> 4) + t2 * 32;              // 0..63 local row
            float z[6];
#pragma unroll
            for (int gi = 0; gi < 6; ++gi) z[gi] = Cs[ml * 97 + hl * 6 + gi] + bcv[gi];
            float c0 = sigf(z[0]) * tanhfast(z[1]);     // forward dir
            float h0 = sigf(z[2]) * tanhfast(c0);
            float c1 = sigf(z[3]) * tanhfast(z[4]);     // backward dir
            float h1 = sigf(z[5]) * tanhfast(c1);

            long m = (long)bm * 256 + p * 64 + ml;
            int hg = bn * 16 + hl;

            if constexpr (LAYER == 0) {                 // inp1T: chunk=(col>>3)*8192+m
                int c0i = hg, c1i = 512 + hg;
                inp1[((long)(c0i >> 3) * 8192 + m) * 8 + (c0i & 7)] = f2bf(h0);
                inp1[((long)(c1i >> 3) * 8192 + m) * 8 + (c1i & 7)] = f2bf(h1);
            }
            store(65536 + m * 1024 + LAYER * 512 + hg, h0 + h1);    // encoder_out
            if ((m & 255) == 255) {                     // t == T-1
                int b = (int)(m >> 8);
                store(LAYER * 16384 + b * 512 + hg, h0);            // h_last (fwd)
                store(32768 + LAYER * 16384 + b * 512 + hg, c0);    // c_last (fwd)
            }
        }
        if (p < 3) __syncthreads();
    }
}

extern "C" void kernel_launch(void* const* d_in, const int* in_sizes, int n_in,
                              void* d_out, int out_size, void* d_ws, size_t ws_size,
                              hipStream_t stream)
{
    const int* x      = (const int*)d_in[0];
    const void* emb   = d_in[1];
    const void* Wih0  = d_in[2];
    const void* bih0  = d_in[4];
    const void* bhh0  = d_in[5];
    const void* Wih1  = d_in[6];
    const void* bih1  = d_in[8];
    const void* bhh1  = d_in[9];

    char* ws = (char*)d_ws;
    int*   flag           = (int*)(ws);
    float* bc0            = (float*)(ws + 1024);
    float* bc1            = (float*)(ws + 16384);
    unsigned short* Wp0   = (unsigned short*)(ws + 32768);
    unsigned short* Wp1   = (unsigned short*)(ws + 4194304);
    unsigned short* e0    = (unsigned short*)(ws + 10485760);
    unsigned short* inp1  = (unsigned short*)(ws + 18874368);

    prep<<<568, 256, 0, stream>>>(x, emb, Wih0, Wih1, bih0, bhh0, bih1, bhh1,
                                  (uint4*)e0, (uint4*)Wp0, (uint4*)Wp1, bc0, bc1, flag);

    gemm_fused<0, 512><<<dim3(32, 32), 512, 0, stream>>>(e0, Wp0, bc0, inp1, d_out, flag);
    gemm_fused<1, 1024><<<dim3(32, 32), 512, 0, stream>>>(inp1, Wp1, bc1, nullptr, d_out, flag);
}